// Round 3
// baseline (352.043 us; speedup 1.0000x reference)
//
#include <hip/hip_runtime.h>
#include <stdint.h>

#define B_ 8
#define T_ 288
#define N_ 307
#define E_ 4912
#define D_ 64

// ============ setup: Q table (288 blocks) + h0 (307 blocks) + CSR (1 block) ============
__global__ __launch_bounds__(64) void k_setup(
    const float* __restrict__ b_val, const float* __restrict__ nfeat,
    const float* __restrict__ W_sta, const float* __restrict__ b_sta,
    const float* __restrict__ ada, const int* __restrict__ src,
    const int* __restrict__ tgt, float* __restrict__ Q, float* __restrict__ h0,
    int* __restrict__ rowstart, int* __restrict__ csr_src) {
    int bid = blockIdx.x, tid = threadIdx.x;
    if (bid < T_) {
        // Q[t,d] = pe(t,d) + b_val[d]
        int t = bid, d = tid;
        int i = d >> 1;
        float div = expf(-(float)(2 * i) * (9.210340371976184f / 64.0f)); // ln(1e4)/64
        float ang = (float)t * div;
        float v = (d & 1) ? cosf(ang) : sinf(ang);
        Q[t * 64 + d] = v + b_val[d];
    } else if (bid < T_ + N_) {
        // h0 = node_features @ W_sta + b_sta + ada
        __shared__ float sf[32];
        int n = bid - T_, d = tid;
        if (d < 32) sf[d] = nfeat[n * 32 + d];
        __syncthreads();
        float a = b_sta[d] + ada[n * 64 + d];
#pragma unroll
        for (int k = 0; k < 32; k++) a += sf[k] * W_sta[k * 64 + d];
        h0[n * 64 + d] = a;
    } else {
        // CSR build (by target), single 64-thread block
        __shared__ int hist[N_];
        __shared__ int offs[N_ + 1];
        __shared__ int cursor[N_];
        for (int i = tid; i < N_; i += 64) hist[i] = 0;
        __syncthreads();
        for (int e = tid; e < E_; e += 64) atomicAdd(&hist[tgt[e]], 1);
        __syncthreads();
        // exclusive prefix scan over 307 counters, 5 chunks of 64 via shuffle
        int run = 0;
#pragma unroll
        for (int c = 0; c < 5; c++) {
            int i = c * 64 + tid;
            int orig = (i < N_) ? hist[i] : 0;
            int v = orig;
#pragma unroll
            for (int off = 1; off < 64; off <<= 1) {
                int u = __shfl_up(v, off);
                if (tid >= off) v += u;
            }
            if (i < N_) offs[i] = run + (v - orig);
            run += __shfl(v, 63);
        }
        if (tid == 0) offs[N_] = run; // == E_
        __syncthreads();
        for (int i = tid; i < N_; i += 64) cursor[i] = offs[i];
        __syncthreads();
        for (int e = tid; e < E_; e += 64) {
            int t = tgt[e];
            int j = atomicAdd(&cursor[t], 1);
            csr_src[j] = src[e];
        }
        __syncthreads();
        for (int i = tid; i <= N_; i += 64) rowstart[i] = offs[i];
    }
}

// ============ projection: p = h_in @ W ; ss/st attention coeffs ============
template <int H, int F>
__global__ __launch_bounds__(64) void k_proj(
    const float* __restrict__ hin, const float* __restrict__ W,
    const float* __restrict__ asrc, const float* __restrict__ atgt,
    float* __restrict__ p, float* __restrict__ ss, float* __restrict__ st) {
    __shared__ float xr[64];
    __shared__ float ps[64];
    int n = blockIdx.x, d = threadIdx.x;
    xr[d] = hin[n * 64 + d];
    __syncthreads();
    float pd = 0.0f;
#pragma unroll
    for (int k = 0; k < 64; k++) pd += xr[k] * W[k * 64 + d];
    p[n * 64 + d] = pd;
    ps[d] = pd;
    __syncthreads();
    if (d < H) {
        float s0 = 0.0f, s1 = 0.0f;
#pragma unroll
        for (int f = 0; f < F; f++) {
            s0 += ps[d * F + f] * asrc[d * F + f];
            s1 += ps[d * F + f] * atgt[d * F + f];
        }
        ss[n * H + d] = s0;
        st[n * H + d] = s1;
    }
}

// ============ gather: softmax-weighted aggregate + skip + bias (+ELU) ============
// softmax computed without segment-max shift (scores are O(1); shift-invariant)
template <int H, int F, bool IDENT, bool LAST>
__global__ __launch_bounds__(64) void k_gat(
    const float* __restrict__ p, const float* __restrict__ ss,
    const float* __restrict__ st, const float* __restrict__ hin,
    const float* __restrict__ skipW, const float* __restrict__ b,
    const int* __restrict__ rowstart, const int* __restrict__ csr_src,
    float* __restrict__ hout) {
    __shared__ float xr[64];
    int n = blockIdx.x, d = threadIdx.x;
    xr[d] = hin[n * 64 + d];
    __syncthreads();
    int h = d / F; // compile-time: F=8 -> d>>3 ; F=64 -> 0
    float stn = st[n * H + h];
    int rs = rowstart[n], re = rowstart[n + 1];
    float den = 0.0f, acc = 0.0f;
    for (int j = rs; j < re; j++) {
        int s = csr_src[j];
        float sc = ss[s * H + h] + stn;
        sc = sc > 0.0f ? sc : 0.2f * sc;   // leaky_relu(0.2)
        float ev = expf(sc);
        den += ev;
        acc += p[s * 64 + d] * ev;
    }
    float val = acc / (den + 1e-16f);
    float sk;
    if (IDENT) {
        sk = xr[d];
    } else {
        sk = 0.0f;
#pragma unroll
        for (int k = 0; k < 64; k++) sk += xr[k] * skipW[k * 64 + d];
    }
    val += sk + b[d];
    if (!LAST) val = val > 0.0f ? val : expm1f(val);  // elu
    hout[n * 64 + d] = val;
}

// ============ broadcast: out[b,t,n,d] = x*Wv[d] + Q[t,d] + h3[n,d] ============
__global__ __launch_bounds__(256) void k_big(const float* __restrict__ x,
                                             const float* __restrict__ Q,
                                             const float* __restrict__ Wv,
                                             const float* __restrict__ h3,
                                             float* __restrict__ out) {
    int row = blockIdx.x * 32 + (threadIdx.x >> 3);   // (b,t,n) linear
    int l8 = threadIdx.x & 7;
    int d0 = l8 * 8;
    int n = row % N_;
    int bt = row / N_;
    int t = bt % T_;
    float xv = x[row];
    float4 q0 = *(const float4*)(Q + t * 64 + d0);
    float4 q1 = *(const float4*)(Q + t * 64 + d0 + 4);
    float4 g0 = *(const float4*)(h3 + n * 64 + d0);
    float4 g1 = *(const float4*)(h3 + n * 64 + d0 + 4);
    float4 w0 = *(const float4*)(Wv + d0);
    float4 w1 = *(const float4*)(Wv + d0 + 4);
    float4 o0, o1;
    o0.x = fmaf(xv, w0.x, q0.x + g0.x);
    o0.y = fmaf(xv, w0.y, q0.y + g0.y);
    o0.z = fmaf(xv, w0.z, q0.z + g0.z);
    o0.w = fmaf(xv, w0.w, q0.w + g0.w);
    o1.x = fmaf(xv, w1.x, q1.x + g1.x);
    o1.y = fmaf(xv, w1.y, q1.y + g1.y);
    o1.z = fmaf(xv, w1.z, q1.z + g1.z);
    o1.w = fmaf(xv, w1.w, q1.w + g1.w);
    float* op = out + row * 64 + d0;
    *(float4*)(op) = o0;
    *(float4*)(op + 4) = o1;
}

extern "C" void kernel_launch(void* const* d_in, const int* in_sizes, int n_in,
                              void* d_out, int out_size, void* d_ws, size_t ws_size,
                              hipStream_t stream) {
    const float* x      = (const float*)d_in[0];
    const float* nfeat  = (const float*)d_in[1];
    const int*   eidx   = (const int*)d_in[2];
    // d_in[3] edge_prob unused (load_trans_prob=False)
    const float* W_val  = (const float*)d_in[4];
    const float* b_val  = (const float*)d_in[5];
    const float* W_sta  = (const float*)d_in[6];
    const float* b_sta  = (const float*)d_in[7];
    const float* ada    = (const float*)d_in[8];
    const float* g0W    = (const float*)d_in[9];
    const float* g0as   = (const float*)d_in[10];
    const float* g0at   = (const float*)d_in[11];
    const float* g0b    = (const float*)d_in[12];
    const float* g1W    = (const float*)d_in[13];
    const float* g1as   = (const float*)d_in[14];
    const float* g1at   = (const float*)d_in[15];
    const float* g1b    = (const float*)d_in[16];
    const float* g2W    = (const float*)d_in[17];
    const float* g2as   = (const float*)d_in[18];
    const float* g2at   = (const float*)d_in[19];
    const float* g2b    = (const float*)d_in[20];
    const float* g0skip = (const float*)d_in[21];
    const float* g1skip = (const float*)d_in[22];
    (void)in_sizes; (void)n_in; (void)out_size; (void)ws_size;

    const int* src = eidx;
    const int* tgt = eidx + E_;

    // workspace layout (fp32 / int32)
    float* ws   = (float*)d_ws;
    float* Q    = ws;                 // 288*64
    float* h0   = Q + T_ * 64;        // 307*64
    float* h1   = h0 + N_ * 64;
    float* h2   = h1 + N_ * 64;
    float* h3   = h2 + N_ * 64;
    float* p    = h3 + N_ * 64;
    float* ss   = p + N_ * 64;        // 307*8 (max)
    float* st   = ss + N_ * 8;
    int* rowstart = (int*)(st + N_ * 8);  // N_+1
    int* csr_src  = rowstart + (N_ + 1);  // E_

    // setup: Q, h0, CSR
    k_setup<<<T_ + N_ + 1, 64, 0, stream>>>(b_val, nfeat, W_sta, b_sta, ada,
                                            src, tgt, Q, h0, rowstart, csr_src);

    // layer 0: H=8, F=8, projected skip, ELU
    k_proj<8, 8><<<N_, 64, 0, stream>>>(h0, g0W, g0as, g0at, p, ss, st);
    k_gat<8, 8, false, false><<<N_, 64, 0, stream>>>(p, ss, st, h0, g0skip, g0b,
                                                     rowstart, csr_src, h1);
    // layer 1: H=8, F=8, projected skip, ELU
    k_proj<8, 8><<<N_, 64, 0, stream>>>(h1, g1W, g1as, g1at, p, ss, st);
    k_gat<8, 8, false, false><<<N_, 64, 0, stream>>>(p, ss, st, h1, g1skip, g1b,
                                                     rowstart, csr_src, h2);
    // layer 2: H=1, F=64, identity skip, no activation
    k_proj<1, 64><<<N_, 64, 0, stream>>>(h2, g2W, g2as, g2at, p, ss, st);
    k_gat<1, 64, true, true><<<N_, 64, 0, stream>>>(p, ss, st, h2, (const float*)nullptr,
                                                    g2b, rowstart, csr_src, h3);

    // broadcast: 707328 rows, 32 rows/block
    const int ROWS = B_ * T_ * N_;                 // 707328
    k_big<<<ROWS / 32, 256, 0, stream>>>(x, Q, W_val, h3, (float*)d_out);
}